// Round 1
// baseline (223.449 us; speedup 1.0000x reference)
//
#include <hip/hip_runtime.h>

// FFM forward: out[b] = sigmoid( linear(b) + 0.5 * sum_k( s_k^2 - sq_k ) )
//   field_f[b,g,k] = sum_d dense_x[b,d]*v[d,g,k] + sum_i v[idx_i, g, k]
//   s_k = sum_g f, sq_k = sum_g f^2
//
// One wave (64 lanes) per batch row. v rows are 312 f32 = 78 float4;
// lane covers float4 slots {lane, 64+lane(<78)} -> fixed k-half per lane,
// so reductions are shfl_xor only (no LDS).

constexpr int ND  = 13;     // dense features
constexpr int NS  = 26;     // sparse features
constexpr int OH  = 1000;   // one-hot dim per sparse feature
constexpr int GK  = 312;    // field_num * k = 39*8 floats per v row
constexpr int GK4 = 78;     // float4 per v row

__global__ __launch_bounds__(256) void ffm_fwd(
    const float* __restrict__ dense_x,   // [B,13]
    const int*   __restrict__ sparse_x,  // [B,26]
    const float* __restrict__ W,         // [26013]
    const float* __restrict__ bias,      // [1]
    const float* __restrict__ v,         // [26013,39,8]
    float*       __restrict__ out,       // [B]
    int nrows)
{
    const int lane = (int)(threadIdx.x & 63u);
    const int row  = (int)((blockIdx.x << 2) + (threadIdx.x >> 6));
    if (row >= nrows) return;

    const float4* __restrict__ v4 = reinterpret_cast<const float4*>(v);
    const bool act1 = lane < (GK4 - 64);   // lanes 0..13 own slot 64+lane

    float a0x = 0.f, a0y = 0.f, a0z = 0.f, a0w = 0.f;
    float a1x = 0.f, a1y = 0.f, a1z = 0.f, a1w = 0.f;

    // ---- dense contribution: f[g,k] += sum_d x_d * v[d,g,k]  (v[:13] is L1-hot)
    #pragma unroll
    for (int d = 0; d < ND; ++d) {
        const float x = dense_x[row * ND + d];        // wave-uniform broadcast
        const float4 p0 = v4[d * GK4 + lane];
        a0x = fmaf(x, p0.x, a0x);
        a0y = fmaf(x, p0.y, a0y);
        a0z = fmaf(x, p0.z, a0z);
        a0w = fmaf(x, p0.w, a0w);
        if (act1) {
            const float4 p1 = v4[d * GK4 + 64 + lane];
            a1x = fmaf(x, p1.x, a1x);
            a1y = fmaf(x, p1.y, a1y);
            a1z = fmaf(x, p1.z, a1z);
            a1w = fmaf(x, p1.w, a1w);
        }
    }

    // ---- sparse gathers: 26 rows of 1248B, fully coalesced float4 loads
    #pragma unroll
    for (int i = 0; i < NS; ++i) {
        const int idx = sparse_x[row * NS + i] + ND + i * OH;
        const float4* __restrict__ vr = v4 + (size_t)idx * GK4;
        const float4 p0 = vr[lane];
        a0x += p0.x; a0y += p0.y; a0z += p0.z; a0w += p0.w;
        if (act1) {
            const float4 p1 = vr[64 + lane];
            a1x += p1.x; a1y += p1.y; a1z += p1.z; a1w += p1.w;
        }
    }

    // ---- linear part: lanes 0..25 gather W[idx], lanes 0..12 add dense dot
    float lin = 0.f;
    if (lane < NS) {
        const int idx = sparse_x[row * NS + lane] + ND + lane * OH;
        lin = W[idx];
    }
    if (lane < ND) {
        lin = fmaf(dense_x[row * ND + lane], W[lane], lin);
    }

    // ---- per-k reductions. Lane parity fixes the k-half; slots differ only in g.
    float sx = a0x + a1x, sy = a0y + a1y, sz = a0z + a1z, sw = a0w + a1w;
    float qx = fmaf(a0x, a0x, a1x * a1x);
    float qy = fmaf(a0y, a0y, a1y * a1y);
    float qz = fmaf(a0z, a0z, a1z * a1z);
    float qw = fmaf(a0w, a0w, a1w * a1w);

    #pragma unroll
    for (int m = 2; m <= 32; m <<= 1) {   // combine lanes of equal parity (same k-half)
        sx += __shfl_xor(sx, m); sy += __shfl_xor(sy, m);
        sz += __shfl_xor(sz, m); sw += __shfl_xor(sw, m);
        qx += __shfl_xor(qx, m); qy += __shfl_xor(qy, m);
        qz += __shfl_xor(qz, m); qw += __shfl_xor(qw, m);
    }
    float val = (sx * sx - qx) + (sy * sy - qy) + (sz * sz - qz) + (sw * sw - qw);
    val += __shfl_xor(val, 1);            // add the other k-half

    #pragma unroll
    for (int m = 1; m <= 32; m <<= 1) lin += __shfl_xor(lin, m);

    if (lane == 0) {
        const float t = lin + bias[0] + 0.5f * val;
        out[row] = 1.f / (1.f + __expf(-t));
    }
}

extern "C" void kernel_launch(void* const* d_in, const int* in_sizes, int n_in,
                              void* d_out, int out_size, void* d_ws, size_t ws_size,
                              hipStream_t stream) {
    const float* dense_x  = (const float*)d_in[0];
    const int*   sparse_x = (const int*)d_in[1];
    const float* W        = (const float*)d_in[2];
    const float* bias     = (const float*)d_in[3];
    const float* v        = (const float*)d_in[4];
    float*       out      = (float*)d_out;

    const int nrows  = in_sizes[0] / ND;        // 16384
    const int blocks = (nrows + 3) / 4;         // 4 waves (rows) per 256-thread block
    hipLaunchKernelGGL(ffm_fwd, dim3(blocks), dim3(256), 0, stream,
                       dense_x, sparse_x, W, bias, v, out, nrows);
}

// Round 2
// 181.239 us; speedup vs baseline: 1.2329x; 1.2329x over previous
//
#include <hip/hip_runtime.h>

// FFM forward: out[b] = sigmoid( linear(b) + 0.5 * sum_k( s_k^2 - sq_k ) )
// One wave per batch row; v rows are 312 f32 = 78 float4; lane owns float4
// slots {lane, 64+lane (lanes 0..13)} -> fixed k-half per lane, so the
// per-k reductions are shfl_xor only (no LDS).
//
// R2: indices loaded ONCE (lane i holds idx_i), broadcast via v_readlane so
// all 52 gathers are SGPR-addressed and mutually independent (max MLP);
// second slot load is clamped+masked instead of exec-predicated.

constexpr int ND  = 13;     // dense features
constexpr int NS  = 26;     // sparse features
constexpr int OH  = 1000;   // one-hot dim per sparse feature
constexpr int GK4 = 78;     // float4 per v row (39*8 floats)

__global__ __launch_bounds__(256) void ffm_fwd(
    const float* __restrict__ dense_x,   // [B,13]
    const int*   __restrict__ sparse_x,  // [B,26]
    const float* __restrict__ W,         // [26013]
    const float* __restrict__ bias,      // [1]
    const float* __restrict__ v,         // [26013,39,8]
    float*       __restrict__ out,       // [B]
    int nrows)
{
    const int lane = (int)(threadIdx.x & 63u);
    const int row  = (int)((blockIdx.x << 2) + (threadIdx.x >> 6));
    if (row >= nrows) return;

    const float4* __restrict__ v4 = reinterpret_cast<const float4*>(v);
    const bool  act1  = lane < (GK4 - 64);          // lanes 0..13 own slot 64+lane
    const int   slot2 = 64 + (act1 ? lane : 13);    // clamped: always in-bounds
    const float fm1   = act1 ? 1.f : 0.f;           // accumulate mask for slot2

    // One coalesced load of all 26 indices (lane i holds idx_i) + 13 dense x.
    int   myidx = 0;
    float myx   = 0.f;
    if (lane < NS) myidx = sparse_x[row * NS + lane] + ND + lane * OH;
    if (lane < ND) myx   = dense_x[row * ND + lane];

    float a0x=0.f,a0y=0.f,a0z=0.f,a0w=0.f;
    float a1x=0.f,a1y=0.f,a1z=0.f,a1w=0.f;

    // ---- dense: v[:13] is 16KB, cache-hot; x broadcast from lane d (SGPR)
    #pragma unroll
    for (int d = 0; d < ND; ++d) {
        const float x  = __int_as_float(__builtin_amdgcn_readlane(__float_as_int(myx), d));
        const float xm = x * fm1;
        const float4 p0 = v4[d * GK4 + lane];
        const float4 p1 = v4[d * GK4 + slot2];
        a0x = fmaf(x,  p0.x, a0x); a0y = fmaf(x,  p0.y, a0y);
        a0z = fmaf(x,  p0.z, a0z); a0w = fmaf(x,  p0.w, a0w);
        a1x = fmaf(xm, p1.x, a1x); a1y = fmaf(xm, p1.y, a1y);
        a1z = fmaf(xm, p1.z, a1z); a1w = fmaf(xm, p1.w, a1w);
    }

    // ---- sparse gathers: 26 rows x 2 coalesced float4 loads, all independent.
    // idx broadcast via readlane -> SGPR base address, no per-lane addr VGPRs.
    #pragma unroll
    for (int i = 0; i < NS; ++i) {
        const int idx = __builtin_amdgcn_readlane(myidx, i);
        const float4* __restrict__ vr = v4 + (size_t)idx * GK4;
        const float4 p0 = vr[lane];
        const float4 p1 = vr[slot2];
        a0x += p0.x; a0y += p0.y; a0z += p0.z; a0w += p0.w;
        a1x = fmaf(fm1, p1.x, a1x); a1y = fmaf(fm1, p1.y, a1y);
        a1z = fmaf(fm1, p1.z, a1z); a1w = fmaf(fm1, p1.w, a1w);
    }

    // ---- linear part
    float lin = 0.f;
    if (lane < NS) lin = W[myidx];
    if (lane < ND) lin = fmaf(myx, W[lane], lin);

    // ---- per-k reductions: lanes of equal parity hold the same k-half
    float sx = a0x + a1x, sy = a0y + a1y, sz = a0z + a1z, sw = a0w + a1w;
    float qx = fmaf(a0x, a0x, a1x * a1x);
    float qy = fmaf(a0y, a0y, a1y * a1y);
    float qz = fmaf(a0z, a0z, a1z * a1z);
    float qw = fmaf(a0w, a0w, a1w * a1w);

    #pragma unroll
    for (int m = 2; m <= 32; m <<= 1) {
        sx += __shfl_xor(sx, m); sy += __shfl_xor(sy, m);
        sz += __shfl_xor(sz, m); sw += __shfl_xor(sw, m);
        qx += __shfl_xor(qx, m); qy += __shfl_xor(qy, m);
        qz += __shfl_xor(qz, m); qw += __shfl_xor(qw, m);
    }
    float val = (sx * sx - qx) + (sy * sy - qy) + (sz * sz - qz) + (sw * sw - qw);
    val += __shfl_xor(val, 1);            // add the other k-half

    #pragma unroll
    for (int m = 1; m <= 32; m <<= 1) lin += __shfl_xor(lin, m);

    if (lane == 0) {
        const float t = lin + bias[0] + 0.5f * val;
        out[row] = 1.f / (1.f + __expf(-t));
    }
}

extern "C" void kernel_launch(void* const* d_in, const int* in_sizes, int n_in,
                              void* d_out, int out_size, void* d_ws, size_t ws_size,
                              hipStream_t stream) {
    const float* dense_x  = (const float*)d_in[0];
    const int*   sparse_x = (const int*)d_in[1];
    const float* W        = (const float*)d_in[2];
    const float* bias     = (const float*)d_in[3];
    const float* v        = (const float*)d_in[4];
    float*       out      = (float*)d_out;

    const int nrows  = in_sizes[0] / ND;        // 16384
    const int blocks = (nrows + 3) / 4;         // 4 waves (rows) per 256-thread block
    hipLaunchKernelGGL(ffm_fwd, dim3(blocks), dim3(256), 0, stream,
                       dense_x, sparse_x, W, bias, v, out, nrows);
}

// Round 4
// 146.173 us; speedup vs baseline: 1.5287x; 1.2399x over previous
//
#include <hip/hip_runtime.h>

// FFM forward: out[b] = sigmoid( linear(b) + 0.5 * sum_k( s_k^2 - sq_k ) )
// One wave per batch row. v rows are 312 f32 = 78 float4 = 1248 B.
// R4: LDS-DMA gather pipeline (global_load_lds, zero dest VGPRs), 3 buffers,
// counted vmcnt(8/4/0). RACE FIX vs R3: consume -> s_waitcnt lgkmcnt(0) ->
// issue, so a buffer's ds_reads are retired before the overwriting DMA is
// issued (R3 let the DMA's LDS write overtake queued ds_reads -> absmax 3e-2).

constexpr int ND   = 13;     // dense features
constexpr int NS   = 26;     // sparse features
constexpr int OH   = 1000;   // one-hot dim per sparse feature
constexpr int GK4  = 78;     // float4 per v row
constexpr int ROWB = 1248;   // bytes per v row
// LDS slot = 1280 B = 80 float4; [1248,1280) is clamp-garbage pad, never read.

__device__ __forceinline__ void gl_lds_16(const void* g, void* l) {
    __builtin_amdgcn_global_load_lds(
        (const __attribute__((address_space(1))) void*)g,
        (__attribute__((address_space(3))) void*)l, 16, 0, 0);
}
__device__ __forceinline__ void gl_lds_4(const void* g, void* l) {
    __builtin_amdgcn_global_load_lds(
        (const __attribute__((address_space(1))) void*)g,
        (__attribute__((address_space(3))) void*)l, 4, 0, 0);
}

__global__ __launch_bounds__(256, 4) void ffm_fwd(
    const float* __restrict__ dense_x,   // [B,13]
    const int*   __restrict__ sparse_x,  // [B,26]
    const float* __restrict__ W,         // [26013]
    const float* __restrict__ bias,      // [1]
    const float* __restrict__ v,         // [26013,39,8]
    float*       __restrict__ out,       // [B]
    int nrows)
{
    // [wave][buffer][rowInBatch][float4 slot]  -> 4*3*2*80*16 = 30720 B
    __shared__ float4 smem[4][3][2][80];

    const int lane = (int)(threadIdx.x & 63u);
    const int wid  = (int)(threadIdx.x >> 6);
    const int row  = (int)(blockIdx.x * 4 + wid);
    if (row >= nrows) return;

    const bool  act1  = lane < (GK4 - 64);          // lanes 0..13 own slot 64+lane
    const int   slot2 = 64 + (act1 ? lane : 13);    // clamped, always in-bounds
    const float fm1   = act1 ? 1.f : 0.f;

    // One coalesced load of all 26 indices (lane i holds idx_i) + 13 dense x.
    int   myidx = 0;
    float myx   = 0.f;
    if (lane < NS) myidx = sparse_x[row * NS + lane] + ND + lane * OH;
    if (lane < ND) myx   = dense_x[row * ND + lane];

    float a0x=0.f,a0y=0.f,a0z=0.f,a0w=0.f;
    float a1x=0.f,a1y=0.f,a1z=0.f,a1w=0.f;

    // ---- dense: v[:13] is 16KB, cache-hot; x broadcast from lane d
    const float4* __restrict__ v4 = reinterpret_cast<const float4*>(v);
    #pragma unroll
    for (int d = 0; d < ND; ++d) {
        const float x  = __int_as_float(__builtin_amdgcn_readlane(__float_as_int(myx), d));
        const float xm = x * fm1;
        const float4 p0 = v4[d * GK4 + lane];
        const float4 p1 = v4[d * GK4 + slot2];
        a0x = fmaf(x,  p0.x, a0x); a0y = fmaf(x,  p0.y, a0y);
        a0z = fmaf(x,  p0.z, a0z); a0w = fmaf(x,  p0.w, a0w);
        a1x = fmaf(xm, p1.x, a1x); a1y = fmaf(xm, p1.y, a1y);
        a1z = fmaf(xm, p1.z, a1z); a1w = fmaf(xm, p1.w, a1w);
    }

    // ---- linear part (all its vmem consumed before the pipeline)
    float lin = 0.f;
    if (lane < NS) lin = W[myidx];
    if (lane < ND) lin = fmaf(myx, W[lane], lin);

    // ---- per-lane byte offsets within a gathered row
    const char* __restrict__ vb = reinterpret_cast<const char*>(v);
    const int off0 = lane << 4;                              // lanes 0..63: [0,1024)
    const int off1 = 1024 + (lane < 56 ? (lane << 2) : 220); // lanes 0..55: [1024,1248)

    // Issue batch b (rows 2b, 2b+1) into LDS buffer `buf`. Zero dest VGPRs.
    auto issue = [&](int b, int buf) {
        #pragma unroll
        for (int j = 0; j < 2; ++j) {
            const int idx = __builtin_amdgcn_readlane(myidx, 2 * b + j);
            const char* rp = vb + (size_t)(unsigned)idx * ROWB;
            gl_lds_16(rp + off0, &smem[wid][buf][j][0]);   // HW: lds_base + lane*16
            gl_lds_4 (rp + off1, &smem[wid][buf][j][64]);  // HW: lds_base + lane*4
        }
    };
    // Accumulate batch b from LDS buffer `buf`.
    auto consume = [&](int buf) {
        #pragma unroll
        for (int j = 0; j < 2; ++j) {
            const float4 p0 = smem[wid][buf][j][lane];
            const float4 p1 = smem[wid][buf][j][slot2];
            a0x += p0.x; a0y += p0.y; a0z += p0.z; a0w += p0.w;
            a1x = fmaf(fm1, p1.x, a1x); a1y = fmaf(fm1, p1.y, a1y);
            a1z = fmaf(fm1, p1.z, a1z); a1w = fmaf(fm1, p1.w, a1w);
        }
    };

    // Drain the VMEM FIFO so vmcnt counting below is exact.
    asm volatile("s_waitcnt vmcnt(0)" ::: "memory");

    issue(0, 0);
    issue(1, 1);
    issue(2, 2);
    #pragma unroll
    for (int b = 0; b < 13; ++b) {
        // Outstanding before wait: {b, b+1, b+2} (clipped at 13). Retire batch b:
        if (b <= 10)      asm volatile("s_waitcnt vmcnt(8)" ::: "memory");
        else if (b == 11) asm volatile("s_waitcnt vmcnt(4)" ::: "memory");
        else              asm volatile("s_waitcnt vmcnt(0)" ::: "memory");
        __builtin_amdgcn_sched_barrier(0);
        consume(b % 3);
        // Buffer-reuse guard: ds_reads must have DELIVERED before the DMA that
        // overwrites this buffer is issued (this was R3's race).
        asm volatile("s_waitcnt lgkmcnt(0)" ::: "memory");
        __builtin_amdgcn_sched_barrier(0);
        if (b + 3 < 13) issue(b + 3, (b + 3) % 3);
    }

    // ---- per-k reductions: lanes of equal parity hold the same k-half
    float sx = a0x + a1x, sy = a0y + a1y, sz = a0z + a1z, sw = a0w + a1w;
    float qx = fmaf(a0x, a0x, a1x * a1x);
    float qy = fmaf(a0y, a0y, a1y * a1y);
    float qz = fmaf(a0z, a0z, a1z * a1z);
    float qw = fmaf(a0w, a0w, a1w * a1w);

    #pragma unroll
    for (int m = 2; m <= 32; m <<= 1) {
        sx += __shfl_xor(sx, m); sy += __shfl_xor(sy, m);
        sz += __shfl_xor(sz, m); sw += __shfl_xor(sw, m);
        qx += __shfl_xor(qx, m); qy += __shfl_xor(qy, m);
        qz += __shfl_xor(qz, m); qw += __shfl_xor(qw, m);
    }
    float val = (sx * sx - qx) + (sy * sy - qy) + (sz * sz - qz) + (sw * sw - qw);
    val += __shfl_xor(val, 1);            // add the other k-half

    #pragma unroll
    for (int m = 1; m <= 32; m <<= 1) lin += __shfl_xor(lin, m);

    if (lane == 0) {
        const float t = lin + bias[0] + 0.5f * val;
        out[row] = 1.f / (1.f + __expf(-t));
    }
}

extern "C" void kernel_launch(void* const* d_in, const int* in_sizes, int n_in,
                              void* d_out, int out_size, void* d_ws, size_t ws_size,
                              hipStream_t stream) {
    const float* dense_x  = (const float*)d_in[0];
    const int*   sparse_x = (const int*)d_in[1];
    const float* W        = (const float*)d_in[2];
    const float* bias     = (const float*)d_in[3];
    const float* v        = (const float*)d_in[4];
    float*       out      = (float*)d_out;

    const int nrows  = in_sizes[0] / ND;        // 16384
    const int blocks = (nrows + 3) / 4;         // 4 waves (rows) per 256-thread block
    hipLaunchKernelGGL(ffm_fwd, dim3(blocks), dim3(256), 0, stream,
                       dense_x, sparse_x, W, bias, v, out, nrows);
}

// Round 6
// 146.087 us; speedup vs baseline: 1.5296x; 1.0006x over previous
//
#include <hip/hip_runtime.h>

// FFM forward: out[b] = sigmoid( linear(b) + 0.5 * sum_k( s_k^2 - sq_k ) )
// One wave per batch row; v rows are 312 f32 = 78 float4 = 1248 B.
// R6 = R5 (rotating-register direct-to-VGPR gather pipeline, grouped tails)
// + CONSOLIDATION FIX: R5 scattered each tail slot's row-partials across
// lanes {j,14+j,28+j,42+j}, then squared PARTIAL sums -> sq_k wrong
// (absmax 6.6e-2). Before the s/sq reduction we now fold the 4 partials
// onto lane j (3 computed-source shuffles per component), restoring the
// R4-verified invariant: each f[g][k] fully materialized in one lane.

constexpr int ND   = 13;     // dense features
constexpr int NS   = 26;     // sparse features
constexpr int OH   = 1000;   // one-hot dim per sparse feature
constexpr int GK4  = 78;     // float4 per v row
constexpr int ROWB = 1248;   // bytes per v row

__global__ __launch_bounds__(256, 4) void ffm_fwd(
    const float* __restrict__ dense_x,   // [B,13]
    const int*   __restrict__ sparse_x,  // [B,26]
    const float* __restrict__ W,         // [26013]
    const float* __restrict__ bias,      // [1]
    const float* __restrict__ v,         // [26013,39,8]
    float*       __restrict__ out,       // [B]
    int nrows)
{
    const int lane = (int)(threadIdx.x & 63u);
    const int row  = (int)(blockIdx.x * 4 + (threadIdx.x >> 6));
    if (row >= nrows) return;

    const float4* __restrict__ v4 = reinterpret_cast<const float4*>(v);
    const char*   __restrict__ vb = reinterpret_cast<const char*>(v);

    const bool  act1  = lane < (GK4 - 64);          // lanes 0..13 own slot 64+lane (dense)
    const int   slot2 = 64 + (act1 ? lane : 13);    // clamped, always in-bounds
    const float fm1   = act1 ? 1.f : 0.f;

    // One coalesced load of all 26 indices (lane i holds idx_i) + 13 dense x.
    int   myidx = 0;
    float myx   = 0.f;
    if (lane < NS) myidx = sparse_x[row * NS + lane] + ND + lane * OH;
    if (lane < ND) myx   = dense_x[row * ND + lane];

    // ---- linear part (issued early; tiny)
    float lin = 0.f;
    if (lane < NS) lin = W[myidx];
    if (lane < ND) lin = fmaf(myx, W[lane], lin);

    float a0x=0.f,a0y=0.f,a0z=0.f,a0w=0.f;
    float a1x=0.f,a1y=0.f,a1z=0.f,a1w=0.f;

    // ---- dense: v[:13] is 16KB, cache-hot; x broadcast from lane d
    #pragma unroll
    for (int d = 0; d < ND; ++d) {
        const float x  = __int_as_float(__builtin_amdgcn_readlane(__float_as_int(myx), d));
        const float xm = x * fm1;
        const float4 p0 = v4[d * GK4 + lane];
        const float4 p1 = v4[d * GK4 + slot2];
        a0x = fmaf(x,  p0.x, a0x); a0y = fmaf(x,  p0.y, a0y);
        a0z = fmaf(x,  p0.z, a0z); a0w = fmaf(x,  p0.w, a0w);
        a1x = fmaf(xm, p1.x, a1x); a1y = fmaf(xm, p1.y, a1y);
        a1z = fmaf(xm, p1.z, a1z); a1w = fmaf(xm, p1.w, a1w);
    }

    // ---- sparse gather pipeline ----
    // Tail-group lane mapping: lane = 14*member + j  (member 0..3, j 0..13).
    const int   lane14 = lane / 14;              // row-group member
    const int   lanej  = lane - lane14 * 14;     // tail slot j
    const float fmT    = (lane < 56) ? 1.f : 0.f;   // groups 0..5: 4 rows each
    const float fmT6   = (lane < 28) ? 1.f : 0.f;   // group 6: rows 24,25 only

    auto mainLoad = [&](int r) -> float4 {       // 64x16B, SGPR base
        const int idx = __builtin_amdgcn_readlane(myidx, r);
        return reinterpret_cast<const float4*>(vb + (size_t)(unsigned)idx * ROWB)[lane];
    };
    auto tailLoad = [&](int g) -> float4 {       // 4 rows' 224B tails, one instr
        int src = 4 * g + lane14;
        src = src > (NS - 1) ? (NS - 1) : src;   // clamp (masked on consume)
        const int idx = __shfl(myidx, src);
        return *reinterpret_cast<const float4*>(
            vb + (size_t)(unsigned)idx * ROWB + 1024 + (lanej << 4));
    };

    float4 m[6], t[2];
    #pragma unroll
    for (int r = 0; r < 6; ++r) m[r] = mainLoad(r);   // prologue: 6 mains
    t[0] = tailLoad(0);
    t[1] = tailLoad(1);                               // + 2 tail groups
    __builtin_amdgcn_sched_barrier(0);

    #pragma unroll
    for (int r = 0; r < NS; ++r) {
        const float4 p0 = m[r % 6];                   // consume main row r
        a0x += p0.x; a0y += p0.y; a0z += p0.z; a0w += p0.w;
        if (r + 6 < NS) m[r % 6] = mainLoad(r + 6);   // refill freed slot
        if ((r & 3) == 0) {
            const int g = r >> 2;                     // consume tail group g
            const float fm = (g == 6) ? fmT6 : fmT;
            const float4 p1 = t[g & 1];
            a1x = fmaf(fm, p1.x, a1x); a1y = fmaf(fm, p1.y, a1y);
            a1z = fmaf(fm, p1.z, a1z); a1w = fmaf(fm, p1.w, a1w);
            if (g + 2 <= 6) t[g & 1] = tailLoad(g + 2);
        }
        __builtin_amdgcn_sched_barrier(0);            // pin pipeline shape
    }

    // ---- CONSOLIDATE tail partials (the R5 bug fix) ----
    // Tail slot 64+j's row-partials live at lanes {j, 14+j, 28+j, 42+j}
    // (dense partial already on lane j). Fold onto lane j; zero elsewhere.
    {
        const float fmc = (lane < 14) ? 1.f : 0.f;
        float bx = a1x + __shfl(a1x, lane + 14) + __shfl(a1x, lane + 28) + __shfl(a1x, lane + 42);
        float by = a1y + __shfl(a1y, lane + 14) + __shfl(a1y, lane + 28) + __shfl(a1y, lane + 42);
        float bz = a1z + __shfl(a1z, lane + 14) + __shfl(a1z, lane + 28) + __shfl(a1z, lane + 42);
        float bw = a1w + __shfl(a1w, lane + 14) + __shfl(a1w, lane + 28) + __shfl(a1w, lane + 42);
        a1x = bx * fmc; a1y = by * fmc; a1z = bz * fmc; a1w = bw * fmc;
    }

    // ---- per-k reductions: lanes/slots of equal parity hold the same k-half
    float sx = a0x + a1x, sy = a0y + a1y, sz = a0z + a1z, sw = a0w + a1w;
    float qx = fmaf(a0x, a0x, a1x * a1x);
    float qy = fmaf(a0y, a0y, a1y * a1y);
    float qz = fmaf(a0z, a0z, a1z * a1z);
    float qw = fmaf(a0w, a0w, a1w * a1w);

    #pragma unroll
    for (int mk = 2; mk <= 32; mk <<= 1) {
        sx += __shfl_xor(sx, mk); sy += __shfl_xor(sy, mk);
        sz += __shfl_xor(sz, mk); sw += __shfl_xor(sw, mk);
        qx += __shfl_xor(qx, mk); qy += __shfl_xor(qy, mk);
        qz += __shfl_xor(qz, mk); qw += __shfl_xor(qw, mk);
    }
    float val = (sx * sx - qx) + (sy * sy - qy) + (sz * sz - qz) + (sw * sw - qw);
    val += __shfl_xor(val, 1);            // add the other k-half

    #pragma unroll
    for (int mk = 1; mk <= 32; mk <<= 1) lin += __shfl_xor(lin, mk);

    if (lane == 0) {
        const float tt = lin + bias[0] + 0.5f * val;
        out[row] = 1.f / (1.f + __expf(-tt));
    }
}

extern "C" void kernel_launch(void* const* d_in, const int* in_sizes, int n_in,
                              void* d_out, int out_size, void* d_ws, size_t ws_size,
                              hipStream_t stream) {
    const float* dense_x  = (const float*)d_in[0];
    const int*   sparse_x = (const int*)d_in[1];
    const float* W        = (const float*)d_in[2];
    const float* bias     = (const float*)d_in[3];
    const float* v        = (const float*)d_in[4];
    float*       out      = (float*)d_out;

    const int nrows  = in_sizes[0] / ND;        // 16384
    const int blocks = (nrows + 3) / 4;         // 4 waves (rows) per 256-thread block
    hipLaunchKernelGGL(ffm_fwd, dim3(blocks), dim3(256), 0, stream,
                       dense_x, sparse_x, W, bias, v, out, nrows);
}

// Round 7
// 119.958 us; speedup vs baseline: 1.8627x; 1.2178x over previous
//
#include <hip/hip_runtime.h>

// FFM forward: out[b] = sigmoid( linear(b) + 0.5 * sum_k( s_k^2 - sq_k ) )
// R7 = R6 gather structure, but the sparse-gather table is repacked to bf16
// in d_ws each launch (kernel 1), halving gathered bytes and the L2-miss
// working set (32.5 -> 16.6 MB, rows padded to 640 B = 5 cache lines).
// R6 post-mortem: dur pinned at 73 us across two architectures with equal
// FETCH_SIZE (250 MB @ 3.5 TB/s) -> L2-miss service-rate wall; only fewer
// miss bytes move it. Dense path + W stay exact f32 (only sparse v is
// quantized; predicted output err ~3e-3 vs 2e-2 threshold).
// Slot mapping is IDENTICAL to R6: slot p holds elements [4p,4p+4) (uint2
// of 4 bf16 instead of float4), so the verified parity/consolidation
// reduction carries over unchanged. Fallback to pure-f32 R6 kernel if
// ws_size is too small.

constexpr int ND     = 13;      // dense features
constexpr int NS     = 26;      // sparse features
constexpr int OH     = 1000;    // one-hot dim per sparse feature
constexpr int GK4    = 78;      // 4-element slots per v row (312 floats)
constexpr int ROWB   = 1248;    // f32 row bytes
constexpr int NROWSV = 26013;   // feature_num
constexpr int BSTRIDE= 640;     // bf16 row stride in ws (624 used, 128-aligned)

// ---------------- kernel 1: repack v (f32) -> ws (bf16, padded rows) -------
__global__ __launch_bounds__(256) void cvt_bf16(
    const float4* __restrict__ vin,   // [26013*78] float4
    char*         __restrict__ ws)
{
    const int tid = (int)(blockIdx.x * 256 + threadIdx.x);
    if (tid >= NROWSV * GK4) return;
    const int row = tid / GK4;
    const int p   = tid - row * GK4;
    const float4 f = vin[tid];
    // RNE f32 -> bf16
    auto rne = [](float x) -> unsigned {
        unsigned u = __float_as_uint(x);
        return (u + 0x7FFFu + ((u >> 16) & 1u)) >> 16;
    };
    uint2 o;
    o.x = rne(f.x) | (rne(f.y) << 16);
    o.y = rne(f.z) | (rne(f.w) << 16);
    *reinterpret_cast<uint2*>(ws + (size_t)row * BSTRIDE + (p << 3)) = o;
}

// ---------------- kernel 2: FFM forward, bf16 gather table ------------------
__global__ __launch_bounds__(256, 4) void ffm_fwd_b(
    const float* __restrict__ dense_x,   // [B,13]
    const int*   __restrict__ sparse_x,  // [B,26]
    const float* __restrict__ W,         // [26013]
    const float* __restrict__ bias,      // [1]
    const float* __restrict__ v,         // [26013,39,8] f32 (dense part only)
    const char*  __restrict__ wsb,       // bf16 table, stride 640
    float*       __restrict__ out,       // [B]
    int nrows)
{
    const int lane = (int)(threadIdx.x & 63u);
    const int row  = (int)(blockIdx.x * 4 + (threadIdx.x >> 6));
    if (row >= nrows) return;

    const float4* __restrict__ v4 = reinterpret_cast<const float4*>(v);

    const bool  act1  = lane < (GK4 - 64);          // lanes 0..13 own slot 64+lane (dense)
    const int   slot2 = 64 + (act1 ? lane : 13);    // clamped, always in-bounds
    const float fm1   = act1 ? 1.f : 0.f;

    // One coalesced load of all 26 indices (lane i holds idx_i) + 13 dense x.
    int   myidx = 0;
    float myx   = 0.f;
    if (lane < NS) myidx = sparse_x[row * NS + lane] + ND + lane * OH;
    if (lane < ND) myx   = dense_x[row * ND + lane];

    // ---- linear part (exact f32)
    float lin = 0.f;
    if (lane < NS) lin = W[myidx];
    if (lane < ND) lin = fmaf(myx, W[lane], lin);

    float a0x=0.f,a0y=0.f,a0z=0.f,a0w=0.f;
    float a1x=0.f,a1y=0.f,a1z=0.f,a1w=0.f;

    // ---- dense: exact f32 v[:13] (16KB, L1-hot); x broadcast from lane d
    #pragma unroll
    for (int d = 0; d < ND; ++d) {
        const float x  = __int_as_float(__builtin_amdgcn_readlane(__float_as_int(myx), d));
        const float xm = x * fm1;
        const float4 p0 = v4[d * GK4 + lane];
        const float4 p1 = v4[d * GK4 + slot2];
        a0x = fmaf(x,  p0.x, a0x); a0y = fmaf(x,  p0.y, a0y);
        a0z = fmaf(x,  p0.z, a0z); a0w = fmaf(x,  p0.w, a0w);
        a1x = fmaf(xm, p1.x, a1x); a1y = fmaf(xm, p1.y, a1y);
        a1z = fmaf(xm, p1.z, a1z); a1w = fmaf(xm, p1.w, a1w);
    }

    // ---- sparse gather pipeline over the bf16 table ----
    // Tail-group lane mapping: lane = 14*member + j (member 0..3, j 0..13).
    const int   lane14 = lane / 14;
    const int   lanej  = lane - lane14 * 14;
    const float fmT    = (lane < 56) ? 1.f : 0.f;   // groups 0..5: 4 rows each
    const float fmT6   = (lane < 28) ? 1.f : 0.f;   // group 6: rows 24,25 only

    auto mainLoad = [&](int r) -> uint2 {      // 64x8B: elements [0,256) of row
        const int idx = __builtin_amdgcn_readlane(myidx, r);
        return *reinterpret_cast<const uint2*>(
            wsb + (size_t)(unsigned)idx * BSTRIDE + (lane << 3));
    };
    auto tailLoad = [&](int g) -> uint2 {      // 4 rows' 112B tails, one instr
        int src = 4 * g + lane14;
        src = src > (NS - 1) ? (NS - 1) : src; // clamp (masked on consume)
        const int idx = __shfl(myidx, src);
        return *reinterpret_cast<const uint2*>(
            wsb + (size_t)(unsigned)idx * BSTRIDE + 512 + (lanej << 3));
    };
    auto lo16 = [](unsigned u) -> float { return __uint_as_float(u << 16); };
    auto hi16 = [](unsigned u) -> float { return __uint_as_float(u & 0xFFFF0000u); };

    uint2 m[6], t[2];
    #pragma unroll
    for (int r = 0; r < 6; ++r) m[r] = mainLoad(r);   // prologue: 6 mains
    t[0] = tailLoad(0);
    t[1] = tailLoad(1);                               // + 2 tail groups
    __builtin_amdgcn_sched_barrier(0);

    #pragma unroll
    for (int r = 0; r < NS; ++r) {
        const uint2 q = m[r % 6];                     // consume main row r
        a0x += lo16(q.x); a0y += hi16(q.x);
        a0z += lo16(q.y); a0w += hi16(q.y);
        if (r + 6 < NS) m[r % 6] = mainLoad(r + 6);   // refill freed slot
        if ((r & 3) == 0) {
            const int g = r >> 2;                     // consume tail group g
            const float fm = (g == 6) ? fmT6 : fmT;
            const uint2 qt = t[g & 1];
            a1x = fmaf(fm, lo16(qt.x), a1x); a1y = fmaf(fm, hi16(qt.x), a1y);
            a1z = fmaf(fm, lo16(qt.y), a1z); a1w = fmaf(fm, hi16(qt.y), a1w);
            if (g + 2 <= 6) t[g & 1] = tailLoad(g + 2);
        }
        __builtin_amdgcn_sched_barrier(0);            // pin pipeline shape
    }

    // ---- consolidate tail partials: slot 64+j partials live at lanes
    // {j,14+j,28+j,42+j}; fold onto lane j, zero elsewhere (R6-verified).
    {
        const float fmc = (lane < 14) ? 1.f : 0.f;
        float bx = a1x + __shfl(a1x, lane + 14) + __shfl(a1x, lane + 28) + __shfl(a1x, lane + 42);
        float by = a1y + __shfl(a1y, lane + 14) + __shfl(a1y, lane + 28) + __shfl(a1y, lane + 42);
        float bz = a1z + __shfl(a1z, lane + 14) + __shfl(a1z, lane + 28) + __shfl(a1z, lane + 42);
        float bw = a1w + __shfl(a1w, lane + 14) + __shfl(a1w, lane + 28) + __shfl(a1w, lane + 42);
        a1x = bx * fmc; a1y = by * fmc; a1z = bz * fmc; a1w = bw * fmc;
    }

    // ---- per-k reductions (parity == k-half, unchanged)
    float sx = a0x + a1x, sy = a0y + a1y, sz = a0z + a1z, sw = a0w + a1w;
    float qx = fmaf(a0x, a0x, a1x * a1x);
    float qy = fmaf(a0y, a0y, a1y * a1y);
    float qz = fmaf(a0z, a0z, a1z * a1z);
    float qw = fmaf(a0w, a0w, a1w * a1w);

    #pragma unroll
    for (int mk = 2; mk <= 32; mk <<= 1) {
        sx += __shfl_xor(sx, mk); sy += __shfl_xor(sy, mk);
        sz += __shfl_xor(sz, mk); sw += __shfl_xor(sw, mk);
        qx += __shfl_xor(qx, mk); qy += __shfl_xor(qy, mk);
        qz += __shfl_xor(qz, mk); qw += __shfl_xor(qw, mk);
    }
    float val = (sx * sx - qx) + (sy * sy - qy) + (sz * sz - qz) + (sw * sw - qw);
    val += __shfl_xor(val, 1);            // add the other k-half

    #pragma unroll
    for (int mk = 1; mk <= 32; mk <<= 1) lin += __shfl_xor(lin, mk);

    if (lane == 0) {
        const float tt = lin + bias[0] + 0.5f * val;
        out[row] = 1.f / (1.f + __expf(-tt));
    }
}

// ---------------- fallback: R6-verified pure-f32 kernel ---------------------
__global__ __launch_bounds__(256, 4) void ffm_fwd_f32(
    const float* __restrict__ dense_x, const int* __restrict__ sparse_x,
    const float* __restrict__ W, const float* __restrict__ bias,
    const float* __restrict__ v, float* __restrict__ out, int nrows)
{
    const int lane = (int)(threadIdx.x & 63u);
    const int row  = (int)(blockIdx.x * 4 + (threadIdx.x >> 6));
    if (row >= nrows) return;
    const float4* __restrict__ v4 = reinterpret_cast<const float4*>(v);
    const char*   __restrict__ vb = reinterpret_cast<const char*>(v);
    const bool  act1  = lane < (GK4 - 64);
    const int   slot2 = 64 + (act1 ? lane : 13);
    const float fm1   = act1 ? 1.f : 0.f;
    int   myidx = 0; float myx = 0.f;
    if (lane < NS) myidx = sparse_x[row * NS + lane] + ND + lane * OH;
    if (lane < ND) myx   = dense_x[row * ND + lane];
    float lin = 0.f;
    if (lane < NS) lin = W[myidx];
    if (lane < ND) lin = fmaf(myx, W[lane], lin);
    float a0x=0.f,a0y=0.f,a0z=0.f,a0w=0.f, a1x=0.f,a1y=0.f,a1z=0.f,a1w=0.f;
    #pragma unroll
    for (int d = 0; d < ND; ++d) {
        const float x  = __int_as_float(__builtin_amdgcn_readlane(__float_as_int(myx), d));
        const float xm = x * fm1;
        const float4 p0 = v4[d * GK4 + lane];
        const float4 p1 = v4[d * GK4 + slot2];
        a0x = fmaf(x,p0.x,a0x); a0y = fmaf(x,p0.y,a0y);
        a0z = fmaf(x,p0.z,a0z); a0w = fmaf(x,p0.w,a0w);
        a1x = fmaf(xm,p1.x,a1x); a1y = fmaf(xm,p1.y,a1y);
        a1z = fmaf(xm,p1.z,a1z); a1w = fmaf(xm,p1.w,a1w);
    }
    const int lane14 = lane / 14, lanej = lane - lane14 * 14;
    const float fmT = (lane < 56) ? 1.f : 0.f, fmT6 = (lane < 28) ? 1.f : 0.f;
    auto mainLoad = [&](int r) -> float4 {
        const int idx = __builtin_amdgcn_readlane(myidx, r);
        return reinterpret_cast<const float4*>(vb + (size_t)(unsigned)idx * ROWB)[lane];
    };
    auto tailLoad = [&](int g) -> float4 {
        int src = 4 * g + lane14; src = src > (NS-1) ? (NS-1) : src;
        const int idx = __shfl(myidx, src);
        return *reinterpret_cast<const float4*>(vb + (size_t)(unsigned)idx * ROWB + 1024 + (lanej << 4));
    };
    float4 m[6], t[2];
    #pragma unroll
    for (int r = 0; r < 6; ++r) m[r] = mainLoad(r);
    t[0] = tailLoad(0); t[1] = tailLoad(1);
    __builtin_amdgcn_sched_barrier(0);
    #pragma unroll
    for (int r = 0; r < NS; ++r) {
        const float4 p0 = m[r % 6];
        a0x += p0.x; a0y += p0.y; a0z += p0.z; a0w += p0.w;
        if (r + 6 < NS) m[r % 6] = mainLoad(r + 6);
        if ((r & 3) == 0) {
            const int g = r >> 2;
            const float fm = (g == 6) ? fmT6 : fmT;
            const float4 p1 = t[g & 1];
            a1x = fmaf(fm,p1.x,a1x); a1y = fmaf(fm,p1.y,a1y);
            a1z = fmaf(fm,p1.z,a1z); a1w = fmaf(fm,p1.w,a1w);
            if (g + 2 <= 6) t[g & 1] = tailLoad(g + 2);
        }
        __builtin_amdgcn_sched_barrier(0);
    }
    {
        const float fmc = (lane < 14) ? 1.f : 0.f;
        float bx = a1x + __shfl(a1x,lane+14) + __shfl(a1x,lane+28) + __shfl(a1x,lane+42);
        float by = a1y + __shfl(a1y,lane+14) + __shfl(a1y,lane+28) + __shfl(a1y,lane+42);
        float bz = a1z + __shfl(a1z,lane+14) + __shfl(a1z,lane+28) + __shfl(a1z,lane+42);
        float bw = a1w + __shfl(a1w,lane+14) + __shfl(a1w,lane+28) + __shfl(a1w,lane+42);
        a1x = bx*fmc; a1y = by*fmc; a1z = bz*fmc; a1w = bw*fmc;
    }
    float sx=a0x+a1x, sy=a0y+a1y, sz=a0z+a1z, sw=a0w+a1w;
    float qx=fmaf(a0x,a0x,a1x*a1x), qy=fmaf(a0y,a0y,a1y*a1y);
    float qz=fmaf(a0z,a0z,a1z*a1z), qw=fmaf(a0w,a0w,a1w*a1w);
    #pragma unroll
    for (int mk = 2; mk <= 32; mk <<= 1) {
        sx += __shfl_xor(sx,mk); sy += __shfl_xor(sy,mk);
        sz += __shfl_xor(sz,mk); sw += __shfl_xor(sw,mk);
        qx += __shfl_xor(qx,mk); qy += __shfl_xor(qy,mk);
        qz += __shfl_xor(qz,mk); qw += __shfl_xor(qw,mk);
    }
    float val = (sx*sx-qx) + (sy*sy-qy) + (sz*sz-qz) + (sw*sw-qw);
    val += __shfl_xor(val, 1);
    #pragma unroll
    for (int mk = 1; mk <= 32; mk <<= 1) lin += __shfl_xor(lin, mk);
    if (lane == 0) {
        const float tt = lin + bias[0] + 0.5f * val;
        out[row] = 1.f / (1.f + __expf(-tt));
    }
}

extern "C" void kernel_launch(void* const* d_in, const int* in_sizes, int n_in,
                              void* d_out, int out_size, void* d_ws, size_t ws_size,
                              hipStream_t stream) {
    const float* dense_x  = (const float*)d_in[0];
    const int*   sparse_x = (const int*)d_in[1];
    const float* W        = (const float*)d_in[2];
    const float* bias     = (const float*)d_in[3];
    const float* v        = (const float*)d_in[4];
    float*       out      = (float*)d_out;

    const int nrows  = in_sizes[0] / ND;        // 16384
    const int blocks = (nrows + 3) / 4;

    const size_t need = (size_t)NROWSV * BSTRIDE;   // 16,648,320 B
    if (ws_size >= need) {
        const int ncvt = NROWSV * GK4;
        hipLaunchKernelGGL(cvt_bf16, dim3((ncvt + 255) / 256), dim3(256), 0, stream,
                           reinterpret_cast<const float4*>(v), (char*)d_ws);
        hipLaunchKernelGGL(ffm_fwd_b, dim3(blocks), dim3(256), 0, stream,
                           dense_x, sparse_x, W, bias, v, (const char*)d_ws, out, nrows);
    } else {
        hipLaunchKernelGGL(ffm_fwd_f32, dim3(blocks), dim3(256), 0, stream,
                           dense_x, sparse_x, W, bias, v, out, nrows);
    }
}

// Round 8
// 115.315 us; speedup vs baseline: 1.9377x; 1.0403x over previous
//
#include <hip/hip_runtime.h>

// FFM forward: out[b] = sigmoid( linear(b) + 0.5 * sum_k( s_k^2 - sq_k ) )
// R8: lane-per-field gather. bf16 table (built in d_ws each launch, rows
// padded to 640 B = 5 cache lines). One uint4 (16B) load with lanes 0..38
// covers a WHOLE 624B row: lane g holds elements [8g,8g+8) = field g, all
// k. Sparse: 26 loads/row (was 33); dense from same table: 13 (was 26);
// no tails, no consolidation. Lanes 39..63 clamp into slot 38's cache line
// (zero extra traffic) and are masked before the reduction.
// Reduction: butterfly 8 s_k; sq collapses to ONE scalar (only Sum_k sq_k
// is needed) -> 60 shuffles total.
// R7 post-mortem: gather scaled 0.63x for 0.5x bytes -> partially
// instruction-rate limited; int8 ruled out by error model (3.3e-2 > 2e-2).

constexpr int ND     = 13;      // dense features
constexpr int NS     = 26;      // sparse features
constexpr int OH     = 1000;    // one-hot dim per sparse feature
constexpr int GK4    = 78;      // float4 per f32 v row
constexpr int ROWB   = 1248;    // f32 row bytes
constexpr int NROWSV = 26013;   // feature_num
constexpr int BSTRIDE= 640;     // bf16 row stride in ws (624 used, 128-aligned)
constexpr int NL     = 39;      // uint4 slots per bf16 row (624/16)

// ---------------- kernel 1: repack v (f32) -> ws (bf16, padded rows) -------
// One thread: 32B f32 in (2 float4) -> 16B bf16 out (uint4).
__global__ __launch_bounds__(256) void cvt_bf16(
    const float4* __restrict__ vin,   // [26013*78] float4
    char*         __restrict__ ws)
{
    const int tid = (int)(blockIdx.x * 256 + threadIdx.x);
    if (tid >= NROWSV * NL) return;
    const int row = tid / NL;
    const int p   = tid - row * NL;          // 16B slot within bf16 row
    const float4 f0 = vin[2 * tid];
    const float4 f1 = vin[2 * tid + 1];
    auto rne = [](float x) -> unsigned {     // RNE f32 -> bf16
        unsigned u = __float_as_uint(x);
        return (u + 0x7FFFu + ((u >> 16) & 1u)) >> 16;
    };
    uint4 o;
    o.x = rne(f0.x) | (rne(f0.y) << 16);
    o.y = rne(f0.z) | (rne(f0.w) << 16);
    o.z = rne(f1.x) | (rne(f1.y) << 16);
    o.w = rne(f1.z) | (rne(f1.w) << 16);
    *reinterpret_cast<uint4*>(ws + (size_t)row * BSTRIDE + ((size_t)p << 4)) = o;
}

// ---------------- kernel 2: FFM forward, lane-per-field ---------------------
__global__ __launch_bounds__(256, 4) void ffm_fwd_c(
    const float* __restrict__ dense_x,   // [B,13]
    const int*   __restrict__ sparse_x,  // [B,26]
    const float* __restrict__ W,         // [26013]
    const float* __restrict__ bias,      // [1]
    const char*  __restrict__ wsb,       // bf16 table, stride 640
    float*       __restrict__ out,       // [B]
    int nrows)
{
    const int lane = (int)(threadIdx.x & 63u);
    const int row  = (int)(blockIdx.x * 4 + (threadIdx.x >> 6));
    if (row >= nrows) return;

    const int   g  = lane < NL ? lane : (NL - 1);   // clamped field id
    const float fm = lane < NL ? 1.f : 0.f;         // mask for lanes 39..63
    const size_t goff = (size_t)g << 4;             // byte offset of my slot

    // One coalesced load of all 26 indices (lane i holds idx_i) + 13 dense x.
    int   myidx = 0;
    float myx   = 0.f;
    if (lane < NS) myidx = sparse_x[row * NS + lane] + ND + lane * OH;
    if (lane < ND) myx   = dense_x[row * ND + lane];

    // ---- linear part (exact f32)
    float lin = 0.f;
    if (lane < NS) lin = W[myidx];
    if (lane < ND) lin = fmaf(myx, W[lane], lin);

    auto lo16 = [](unsigned u) -> float { return __uint_as_float(u << 16); };
    auto hi16 = [](unsigned u) -> float { return __uint_as_float(u & 0xFFFF0000u); };

    float a[8];
    #pragma unroll
    for (int j = 0; j < 8; ++j) a[j] = 0.f;

    // ---- dense: rows 0..12 of the bf16 table (8.3KB hot), x broadcast
    #pragma unroll
    for (int d = 0; d < ND; ++d) {
        const float x = __int_as_float(__builtin_amdgcn_readlane(__float_as_int(myx), d));
        const uint4 q = *reinterpret_cast<const uint4*>(wsb + (size_t)d * BSTRIDE + goff);
        a[0] = fmaf(x, lo16(q.x), a[0]); a[1] = fmaf(x, hi16(q.x), a[1]);
        a[2] = fmaf(x, lo16(q.y), a[2]); a[3] = fmaf(x, hi16(q.y), a[3]);
        a[4] = fmaf(x, lo16(q.z), a[4]); a[5] = fmaf(x, hi16(q.z), a[5]);
        a[6] = fmaf(x, lo16(q.w), a[6]); a[7] = fmaf(x, hi16(q.w), a[7]);
    }

    // ---- sparse gathers: ONE uint4 instruction per row, rotating slots
    auto mainLoad = [&](int r) -> uint4 {
        const int idx = __builtin_amdgcn_readlane(myidx, r);   // SGPR base
        return *reinterpret_cast<const uint4*>(
            wsb + (size_t)(unsigned)idx * BSTRIDE + goff);
    };

    uint4 m[6];
    #pragma unroll
    for (int r = 0; r < 6; ++r) m[r] = mainLoad(r);   // prologue
    __builtin_amdgcn_sched_barrier(0);

    #pragma unroll
    for (int r = 0; r < NS; ++r) {
        const uint4 q = m[r % 6];                     // consume row r
        a[0] += lo16(q.x); a[1] += hi16(q.x);
        a[2] += lo16(q.y); a[3] += hi16(q.y);
        a[4] += lo16(q.z); a[5] += hi16(q.z);
        a[6] += lo16(q.w); a[7] += hi16(q.w);
        if (r + 6 < NS) m[r % 6] = mainLoad(r + 6);   // refill freed slot
        __builtin_amdgcn_sched_barrier(0);            // pin pipeline shape
    }

    // ---- mask the clamped lanes, then reduce ----
    // a[j] = f[g][k=j] for lanes g=0..38; 0 elsewhere.
    float s[8];
    float qtot = 0.f;
    #pragma unroll
    for (int j = 0; j < 8; ++j) {
        const float aj = a[j] * fm;
        s[j] = aj;
        qtot = fmaf(aj, aj, qtot);     // sum_k sq_k collapses to one scalar
    }
    #pragma unroll
    for (int mk = 1; mk <= 32; mk <<= 1) {
        #pragma unroll
        for (int j = 0; j < 8; ++j) s[j] += __shfl_xor(s[j], mk);
        qtot += __shfl_xor(qtot, mk);
        lin  += __shfl_xor(lin, mk);
    }
    float val = -qtot;
    #pragma unroll
    for (int j = 0; j < 8; ++j) val = fmaf(s[j], s[j], val);

    if (lane == 0) {
        const float tt = lin + bias[0] + 0.5f * val;
        out[row] = 1.f / (1.f + __expf(-tt));
    }
}

// ---------------- fallback: R6-verified pure-f32 kernel ---------------------
__global__ __launch_bounds__(256, 4) void ffm_fwd_f32(
    const float* __restrict__ dense_x, const int* __restrict__ sparse_x,
    const float* __restrict__ W, const float* __restrict__ bias,
    const float* __restrict__ v, float* __restrict__ out, int nrows)
{
    const int lane = (int)(threadIdx.x & 63u);
    const int row  = (int)(blockIdx.x * 4 + (threadIdx.x >> 6));
    if (row >= nrows) return;
    const float4* __restrict__ v4 = reinterpret_cast<const float4*>(v);
    const char*   __restrict__ vb = reinterpret_cast<const char*>(v);
    const bool  act1  = lane < 14;
    const int   slot2 = 64 + (act1 ? lane : 13);
    const float fm1   = act1 ? 1.f : 0.f;
    int   myidx = 0; float myx = 0.f;
    if (lane < NS) myidx = sparse_x[row * NS + lane] + ND + lane * OH;
    if (lane < ND) myx   = dense_x[row * ND + lane];
    float lin = 0.f;
    if (lane < NS) lin = W[myidx];
    if (lane < ND) lin = fmaf(myx, W[lane], lin);
    float a0x=0.f,a0y=0.f,a0z=0.f,a0w=0.f, a1x=0.f,a1y=0.f,a1z=0.f,a1w=0.f;
    #pragma unroll
    for (int d = 0; d < ND; ++d) {
        const float x  = __int_as_float(__builtin_amdgcn_readlane(__float_as_int(myx), d));
        const float xm = x * fm1;
        const float4 p0 = v4[d * GK4 + lane];
        const float4 p1 = v4[d * GK4 + slot2];
        a0x = fmaf(x,p0.x,a0x); a0y = fmaf(x,p0.y,a0y);
        a0z = fmaf(x,p0.z,a0z); a0w = fmaf(x,p0.w,a0w);
        a1x = fmaf(xm,p1.x,a1x); a1y = fmaf(xm,p1.y,a1y);
        a1z = fmaf(xm,p1.z,a1z); a1w = fmaf(xm,p1.w,a1w);
    }
    const int lane14 = lane / 14, lanej = lane - lane14 * 14;
    const float fmT = (lane < 56) ? 1.f : 0.f, fmT6 = (lane < 28) ? 1.f : 0.f;
    auto mainLoad = [&](int r) -> float4 {
        const int idx = __builtin_amdgcn_readlane(myidx, r);
        return reinterpret_cast<const float4*>(vb + (size_t)(unsigned)idx * ROWB)[lane];
    };
    auto tailLoad = [&](int g2) -> float4 {
        int src = 4 * g2 + lane14; src = src > (NS-1) ? (NS-1) : src;
        const int idx = __shfl(myidx, src);
        return *reinterpret_cast<const float4*>(vb + (size_t)(unsigned)idx * ROWB + 1024 + (lanej << 4));
    };
    float4 m[6], t[2];
    #pragma unroll
    for (int r = 0; r < 6; ++r) m[r] = mainLoad(r);
    t[0] = tailLoad(0); t[1] = tailLoad(1);
    __builtin_amdgcn_sched_barrier(0);
    #pragma unroll
    for (int r = 0; r < NS; ++r) {
        const float4 p0 = m[r % 6];
        a0x += p0.x; a0y += p0.y; a0z += p0.z; a0w += p0.w;
        if (r + 6 < NS) m[r % 6] = mainLoad(r + 6);
        if ((r & 3) == 0) {
            const int g2 = r >> 2;
            const float fmv = (g2 == 6) ? fmT6 : fmT;
            const float4 p1 = t[g2 & 1];
            a1x = fmaf(fmv,p1.x,a1x); a1y = fmaf(fmv,p1.y,a1y);
            a1z = fmaf(fmv,p1.z,a1z); a1w = fmaf(fmv,p1.w,a1w);
            if (g2 + 2 <= 6) t[g2 & 1] = tailLoad(g2 + 2);
        }
        __builtin_amdgcn_sched_barrier(0);
    }
    {
        const float fmc = (lane < 14) ? 1.f : 0.f;
        float bx = a1x + __shfl(a1x,lane+14) + __shfl(a1x,lane+28) + __shfl(a1x,lane+42);
        float by = a1y + __shfl(a1y,lane+14) + __shfl(a1y,lane+28) + __shfl(a1y,lane+42);
        float bz = a1z + __shfl(a1z,lane+14) + __shfl(a1z,lane+28) + __shfl(a1z,lane+42);
        float bw = a1w + __shfl(a1w,lane+14) + __shfl(a1w,lane+28) + __shfl(a1w,lane+42);
        a1x = bx*fmc; a1y = by*fmc; a1z = bz*fmc; a1w = bw*fmc;
    }
    float sx=a0x+a1x, sy=a0y+a1y, sz=a0z+a1z, sw=a0w+a1w;
    float qx=fmaf(a0x,a0x,a1x*a1x), qy=fmaf(a0y,a0y,a1y*a1y);
    float qz=fmaf(a0z,a0z,a1z*a1z), qw=fmaf(a0w,a0w,a1w*a1w);
    #pragma unroll
    for (int mk = 2; mk <= 32; mk <<= 1) {
        sx += __shfl_xor(sx,mk); sy += __shfl_xor(sy,mk);
        sz += __shfl_xor(sz,mk); sw += __shfl_xor(sw,mk);
        qx += __shfl_xor(qx,mk); qy += __shfl_xor(qy,mk);
        qz += __shfl_xor(qz,mk); qw += __shfl_xor(qw,mk);
    }
    float val = (sx*sx-qx) + (sy*sy-qy) + (sz*sz-qz) + (sw*sw-qw);
    val += __shfl_xor(val, 1);
    #pragma unroll
    for (int mk = 1; mk <= 32; mk <<= 1) lin += __shfl_xor(lin, mk);
    if (lane == 0) {
        const float tt = lin + bias[0] + 0.5f * val;
        out[row] = 1.f / (1.f + __expf(-tt));
    }
}

extern "C" void kernel_launch(void* const* d_in, const int* in_sizes, int n_in,
                              void* d_out, int out_size, void* d_ws, size_t ws_size,
                              hipStream_t stream) {
    const float* dense_x  = (const float*)d_in[0];
    const int*   sparse_x = (const int*)d_in[1];
    const float* W        = (const float*)d_in[2];
    const float* bias     = (const float*)d_in[3];
    const float* v        = (const float*)d_in[4];
    float*       out      = (float*)d_out;

    const int nrows  = in_sizes[0] / ND;        // 16384
    const int blocks = (nrows + 3) / 4;

    const size_t need = (size_t)NROWSV * BSTRIDE;   // 16,648,320 B
    if (ws_size >= need) {
        const int ncvt = NROWSV * NL;               // uint4 slots
        hipLaunchKernelGGL(cvt_bf16, dim3((ncvt + 255) / 256), dim3(256), 0, stream,
                           reinterpret_cast<const float4*>(v), (char*)d_ws);
        hipLaunchKernelGGL(ffm_fwd_c, dim3(blocks), dim3(256), 0, stream,
                           dense_x, sparse_x, W, bias, (const char*)d_ws, out, nrows);
    } else {
        hipLaunchKernelGGL(ffm_fwd_f32, dim3(blocks), dim3(256), 0, stream,
                           dense_x, sparse_x, W, bias, v, out, nrows);
    }
}